// Round 5
// baseline (318.643 us; speedup 1.0000x reference)
//
#include <hip/hip_runtime.h>

// B=512, P=64, K=8, D=512, T=50000
// out: [B*P, 2*D] fp32
#define BB 512
#define PP 64
#define KK 8
#define DD 512

typedef float v4f __attribute__((ext_vector_type(4)));

// ---------------------------------------------------------------------------
// Rounds 3-4 post-mortem: the register-MLP plan never executed -- VGPR_Count
// stayed 36 (need >=136 to hold 34 float4 results), i.e. the pressure-driven
// pre-RA scheduler re-serialized the gathers regardless of source order,
// launch_bounds caps, or sched_barrier. Counters were identical across
// rounds 0/3/4: 3.5 TB/s, VALU ~20%, the serialized-gather signature.
//
// Fix: make the loads register-free. global_load_lds is fire-and-forget
// (result goes to LDS, vmcnt-tracked, no destination VGPR), so the compiler
// CANNOT serialize it by register pressure. One wave per row, 32 KB LDS:
//   issue 16 neighbor-row async loads      (vmcnt +16)
//   issue 2 focal register loads           (vmcnt +2)
//   issue 16 title-row async loads         (vmcnt +16)
//   s_waitcnt vmcnt(16)   -> neighbors+focal done, titles STILL IN FLIGHT
//   dots + butterfly reduce + softmax      (title latency hides here)
//   s_waitcnt vmcnt(0)    -> titles done
//   weighted sum from LDS, NT stores
// Per-wave queue depth 34 (was ~2); per-CU outstanding bytes ~170 KB at
// 5 waves/CU (LDS-limited: 160/32 KB) -- far past Little's-law saturation.
// ---------------------------------------------------------------------------

__device__ __forceinline__ void async_1k(const void* g, void* l) {
    // one wave-level 1 KB global->LDS copy: lane i moves 16 B from g+16i
    // to lds_base+16i (HW adds lane*size to the uniform LDS base)
    __builtin_amdgcn_global_load_lds(
        (const __attribute__((address_space(1))) void*)g,
        (__attribute__((address_space(3))) void*)l,
        16, 0, 0);
}

__global__ __launch_bounds__(64) void han_meta_kernel(
    const float* __restrict__ inputs,       // [B,P,D]
    const float* __restrict__ title,        // [T,D]
    const int*   __restrict__ nbr_batch,    // [B,P,K]
    const int*   __restrict__ nbr_job,      // [B,P,K]
    const int*   __restrict__ nbr_title,    // [B,P,K]
    const int*   __restrict__ nbr_mask,     // [B,P,K]
    float*       __restrict__ out)          // [B*P, 2*D]
{
    // 8 neighbor rows (16 KB) + 8 title rows (16 KB)
    __shared__ float lds_f[8192];           // 32 KB -> 5 blocks/CU

    const int lane = threadIdx.x;           // 0..63, one wave per block
    const int row  = __builtin_amdgcn_readfirstlane(blockIdx.x);  // [0, B*P)

    // ---- indices: wave-uniform scalar loads ----
    const int* nb = nbr_batch + row * KK;
    const int* nj = nbr_job   + row * KK;
    const int* nt = nbr_title + row * KK;
    const int* nm = nbr_mask  + row * KK;
    int nbk[KK], njk[KK], ntk[KK], nmk[KK];
    #pragma unroll
    for (int k = 0; k < KK; ++k) {
        nbk[k] = __builtin_amdgcn_readfirstlane(nb[k]);
        njk[k] = __builtin_amdgcn_readfirstlane(nj[k]);
        ntk[k] = __builtin_amdgcn_readfirstlane(nt[k]);
        nmk[k] = __builtin_amdgcn_readfirstlane(nm[k]);
    }

    // ---- scalar byte offsets; masked slots -> cache-hot safe rows ----
    const unsigned focal_off = (unsigned)row * (DD * 4);
    unsigned goff[KK], toff[KK];
    #pragma unroll
    for (int k = 0; k < KK; ++k) {
        goff[k] = nmk[k] ? (unsigned)(nbk[k] * PP + njk[k]) * (DD * 4)
                         : focal_off;                   // focal row (hot)
        toff[k] = nmk[k] ? (unsigned)ntk[k] * (DD * 4)
                         : 0u;                          // title row 0 (hot)
    }

    const char* ibase = (const char*)inputs;
    const char* tbase = (const char*)title;
    char*       lbase = (char*)lds_f;
    const unsigned lo = (unsigned)lane * 16;

    // ---- fire-and-forget: 16 neighbor-row 1 KB async copies ----
    #pragma unroll
    for (int k = 0; k < KK; ++k) {
        async_1k(ibase + goff[k] + lo,        lbase + k * 2048);
        async_1k(ibase + goff[k] + lo + 1024, lbase + k * 2048 + 1024);
    }

    // ---- focal row to registers (issued AFTER neighbors, BEFORE titles,
    //      so vmcnt(16) below covers neighbors+focal) ----
    const float4 fa = *(const float4*)(ibase + focal_off + lo);
    const float4 fb = *(const float4*)(ibase + focal_off + lo + 1024);

    // ---- fire-and-forget: 16 title-row 1 KB async copies ----
    #pragma unroll
    for (int k = 0; k < KK; ++k) {
        async_1k(tbase + toff[k] + lo,        lbase + 16384 + k * 2048);
        async_1k(tbase + toff[k] + lo + 1024, lbase + 16384 + k * 2048 + 1024);
    }

    // ---- wait for neighbors + focal; the 16 title loads stay in flight ----
    asm volatile("s_waitcnt vmcnt(16)" ::: "memory");
    __builtin_amdgcn_sched_barrier(0);

    // ---- dots from LDS (ds_read_b128, contiguous, conflict-free) ----
    const float4* l4 = (const float4*)lds_f;
    float d[KK];
    #pragma unroll
    for (int k = 0; k < KK; ++k) {
        const float4 ga = l4[k * 128 + lane];
        const float4 gb = l4[k * 128 + 64 + lane];
        d[k] = fa.x*ga.x + fa.y*ga.y + fa.z*ga.z + fa.w*ga.w
             + fb.x*gb.x + fb.y*gb.y + fb.z*gb.z + fb.w*gb.w;
    }

    // ---- butterfly reduce all 8 dots (title latency hiding under this) ----
    #pragma unroll
    for (int off = 32; off >= 1; off >>= 1) {
        #pragma unroll
        for (int k = 0; k < KK; ++k)
            d[k] += __shfl_xor(d[k], off, 64);
    }

    // ---- masked softmax over K=8 (replicated per lane; all scalar) ----
    float logit[KK];
    #pragma unroll
    for (int k = 0; k < KK; ++k) logit[k] = nmk[k] ? d[k] : -1e9f;
    float m = logit[0];
    #pragma unroll
    for (int k = 1; k < KK; ++k) m = fmaxf(m, logit[k]);
    float e[KK];
    float s = 0.0f;
    #pragma unroll
    for (int k = 0; k < KK; ++k) {
        e[k] = expf(logit[k] - m);
        s += e[k];
    }
    const float inv = 1.0f / s;
    float w[KK];
    #pragma unroll
    for (int k = 0; k < KK; ++k) w[k] = nmk[k] ? e[k] * inv : 0.0f;

    // ---- titles now needed: drain remaining loads ----
    asm volatile("s_waitcnt vmcnt(0)" ::: "memory");
    __builtin_amdgcn_sched_barrier(0);

    // ---- weighted title sum from LDS (w==0 exactly on masked slots) ----
    float4 oa = make_float4(0.f, 0.f, 0.f, 0.f);
    float4 ob = make_float4(0.f, 0.f, 0.f, 0.f);
    #pragma unroll
    for (int k = 0; k < KK; ++k) {
        const float4 ta = l4[1024 + k * 128 + lane];
        const float4 tb = l4[1024 + k * 128 + 64 + lane];
        oa.x += w[k]*ta.x; oa.y += w[k]*ta.y; oa.z += w[k]*ta.z; oa.w += w[k]*ta.w;
        ob.x += w[k]*tb.x; ob.y += w[k]*tb.y; ob.z += w[k]*tb.z; ob.w += w[k]*tb.w;
    }

    // ---- write: [focal(512) | graph(512)] -- non-temporal (write-once) ----
    v4f* o4 = (v4f*)(out + (size_t)row * (2 * DD));
    v4f va = {fa.x, fa.y, fa.z, fa.w};
    v4f vb = {fb.x, fb.y, fb.z, fb.w};
    v4f vc = {oa.x, oa.y, oa.z, oa.w};
    v4f vd = {ob.x, ob.y, ob.z, ob.w};
    __builtin_nontemporal_store(va, o4 + lane);        // d 0..255
    __builtin_nontemporal_store(vb, o4 + lane + 64);   // d 256..511
    __builtin_nontemporal_store(vc, o4 + lane + 128);  // graph 0..255
    __builtin_nontemporal_store(vd, o4 + lane + 192);  // graph 256..511
}

extern "C" void kernel_launch(void* const* d_in, const int* in_sizes, int n_in,
                              void* d_out, int out_size, void* d_ws, size_t ws_size,
                              hipStream_t stream) {
    const float* inputs    = (const float*)d_in[0];
    const float* title     = (const float*)d_in[1];
    const int*   nbr_batch = (const int*)d_in[2];
    const int*   nbr_job   = (const int*)d_in[3];
    const int*   nbr_title = (const int*)d_in[4];
    const int*   nbr_mask  = (const int*)d_in[5];
    float*       out       = (float*)d_out;

    const int rows = BB * PP;     // 32768
    dim3 grid(rows);              // one wave (64 threads) per row
    dim3 block(64);

    han_meta_kernel<<<grid, block, 0, stream>>>(
        inputs, title, nbr_batch, nbr_job, nbr_title, nbr_mask, out);
}

// Round 6
// 297.572 us; speedup vs baseline: 1.0708x; 1.0708x over previous
//
#include <hip/hip_runtime.h>

// B=512, P=64, K=8, D=512, T=50000
// out: [B*P, 2*D] fp32
#define BB 512
#define PP 64
#define KK 8
#define DD 512

typedef float v4f __attribute__((ext_vector_type(4)));

// ---------------------------------------------------------------------------
// Round-5 post-mortem: full-LDS staging (32 KB/row) collapsed occupancy to
// ~3.4 waves/CU and the predicated masked slots added ~70% request bytes;
// 144 us / 3.0 TB/s. Both were confounds, not a verdict on the MLP theory.
//
// This version deconfounds:
//  - 16 KB LDS per row, TIME-SHARED: neighbors staged async, consumed by the
//    dot phase, then the SAME slice is refilled with titles (issued under the
//    softmax). 128-thr block = 2 rows = 32 KB -> 5 blocks/CU = 10 waves/CU
//    (~31% occupancy, 3x round 5), each with up to 18 loads in flight.
//  - masked slots are branch-skipped (wave-uniform mask -> free branch), so
//    request bytes match the baseline (~18 KB/row avg, not 32 KB).
//  - exactly two full vmcnt drains per row (after neighbors+focal, after
//    titles) instead of ~8 serialized gather round-trips.
// Masked LDS slots contain garbage but are never consumed: dot results are
// discarded by the -1e9 select; the sum phase branch-skips (NaN*0==NaN).
// ---------------------------------------------------------------------------

__device__ __forceinline__ void async_1k(const void* g, void* l) {
    // wave-level 1 KB global->LDS copy: lane i moves 16 B from g+16i to
    // lds_base+16i (HW adds lane*size to the wave-uniform LDS base).
    __builtin_amdgcn_global_load_lds(
        (const __attribute__((address_space(1))) void*)g,
        (__attribute__((address_space(3))) void*)l,
        16, 0, 0);
}

__global__ __launch_bounds__(128) void han_meta_kernel(
    const float* __restrict__ inputs,       // [B,P,D]
    const float* __restrict__ title,        // [T,D]
    const int*   __restrict__ nbr_batch,    // [B,P,K]
    const int*   __restrict__ nbr_job,      // [B,P,K]
    const int*   __restrict__ nbr_title,    // [B,P,K]
    const int*   __restrict__ nbr_mask,     // [B,P,K]
    float*       __restrict__ out)          // [B*P, 2*D]
{
    __shared__ float lds_f[8192];           // 32 KB: 2 waves x 16 KB slices

    const int lane = threadIdx.x & 63;
    const int wrow = threadIdx.x >> 6;      // 0 or 1: which row this wave owns
    const int row  = __builtin_amdgcn_readfirstlane(blockIdx.x * 2 + wrow);

    char* lbase = (char*)(lds_f + wrow * 4096);   // private 16 KB slice

    // ---- indices: wave-uniform scalar loads ----
    const int* nb = nbr_batch + row * KK;
    const int* nj = nbr_job   + row * KK;
    const int* nt = nbr_title + row * KK;
    const int* nm = nbr_mask  + row * KK;
    int nbk[KK], njk[KK], ntk[KK], nmk[KK];
    #pragma unroll
    for (int k = 0; k < KK; ++k) {
        nbk[k] = __builtin_amdgcn_readfirstlane(nb[k]);
        njk[k] = __builtin_amdgcn_readfirstlane(nj[k]);
        ntk[k] = __builtin_amdgcn_readfirstlane(nt[k]);
        nmk[k] = __builtin_amdgcn_readfirstlane(nm[k]);
    }

    const char* ibase = (const char*)inputs;
    const char* tbase = (const char*)title;
    const unsigned focal_off = (unsigned)row * (DD * 4);
    const unsigned lo = (unsigned)lane * 16;

    // ---- stage unmasked neighbor rows into LDS (fire-and-forget) ----
    #pragma unroll
    for (int k = 0; k < KK; ++k) {
        if (nmk[k]) {
            const unsigned go = (unsigned)(nbk[k] * PP + njk[k]) * (DD * 4);
            async_1k(ibase + go + lo,        lbase + k * 2048);
            async_1k(ibase + go + lo + 1024, lbase + k * 2048 + 1024);
        }
    }

    // ---- focal row to registers (in flight together with the asyncs) ----
    const float4 fa = *(const float4*)(ibase + focal_off + lo);
    const float4 fb = *(const float4*)(ibase + focal_off + lo + 1024);

    // one exposed latency for neighbors + focal combined
    asm volatile("s_waitcnt vmcnt(0)" ::: "memory");
    __builtin_amdgcn_sched_barrier(0);

    // ---- dots from LDS (unconditional: masked-slot garbage is discarded
    //      by the -1e9 select below; never multiplied into the output) ----
    const float4* l4 = (const float4*)lbase;
    float d[KK];
    #pragma unroll
    for (int k = 0; k < KK; ++k) {
        const float4 ga = l4[k * 128 + lane];
        const float4 gb = l4[k * 128 + 64 + lane];
        d[k] = fa.x*ga.x + fa.y*ga.y + fa.z*ga.z + fa.w*ga.w
             + fb.x*gb.x + fb.y*gb.y + fb.z*gb.z + fb.w*gb.w;
    }

    // ---- butterfly reduce all 8 dots together ----
    #pragma unroll
    for (int off = 32; off >= 1; off >>= 1) {
        #pragma unroll
        for (int k = 0; k < KK; ++k)
            d[k] += __shfl_xor(d[k], off, 64);
    }

    // all ds_reads (and shuffles) retired -> LDS slice is dead, safe to refill
    asm volatile("s_waitcnt lgkmcnt(0)" ::: "memory");
    __builtin_amdgcn_sched_barrier(0);

    // ---- stage unmasked title rows into the SAME slice (under softmax) ----
    #pragma unroll
    for (int k = 0; k < KK; ++k) {
        if (nmk[k]) {
            const unsigned to = (unsigned)ntk[k] * (DD * 4);
            async_1k(tbase + to + lo,        lbase + k * 2048);
            async_1k(tbase + to + lo + 1024, lbase + k * 2048 + 1024);
        }
    }

    // ---- masked softmax over K=8 (replicated per lane; all scalar) ----
    float logit[KK];
    #pragma unroll
    for (int k = 0; k < KK; ++k) logit[k] = nmk[k] ? d[k] : -1e9f;
    float m = logit[0];
    #pragma unroll
    for (int k = 1; k < KK; ++k) m = fmaxf(m, logit[k]);
    float e[KK];
    float s = 0.0f;
    #pragma unroll
    for (int k = 0; k < KK; ++k) {
        e[k] = expf(logit[k] - m);
        s += e[k];
    }
    const float inv = 1.0f / s;

    // second (and last) exposed latency: titles
    asm volatile("s_waitcnt vmcnt(0)" ::: "memory");
    __builtin_amdgcn_sched_barrier(0);

    // ---- weighted title sum from LDS (branch-skip masked: garbage slots) ----
    float4 oa = make_float4(0.f, 0.f, 0.f, 0.f);
    float4 ob = make_float4(0.f, 0.f, 0.f, 0.f);
    #pragma unroll
    for (int k = 0; k < KK; ++k) {
        if (nmk[k]) {
            const float w = e[k] * inv;
            const float4 ta = l4[k * 128 + lane];
            const float4 tb = l4[k * 128 + 64 + lane];
            oa.x += w*ta.x; oa.y += w*ta.y; oa.z += w*ta.z; oa.w += w*ta.w;
            ob.x += w*tb.x; ob.y += w*tb.y; ob.z += w*tb.z; ob.w += w*tb.w;
        }
    }

    // ---- write: [focal(512) | graph(512)] -- non-temporal (write-once) ----
    v4f* o4 = (v4f*)(out + (size_t)row * (2 * DD));
    v4f va = {fa.x, fa.y, fa.z, fa.w};
    v4f vb = {fb.x, fb.y, fb.z, fb.w};
    v4f vc = {oa.x, oa.y, oa.z, oa.w};
    v4f vd = {ob.x, ob.y, ob.z, ob.w};
    __builtin_nontemporal_store(va, o4 + lane);        // d 0..255
    __builtin_nontemporal_store(vb, o4 + lane + 64);   // d 256..511
    __builtin_nontemporal_store(vc, o4 + lane + 128);  // graph 0..255
    __builtin_nontemporal_store(vd, o4 + lane + 192);  // graph 256..511
}

extern "C" void kernel_launch(void* const* d_in, const int* in_sizes, int n_in,
                              void* d_out, int out_size, void* d_ws, size_t ws_size,
                              hipStream_t stream) {
    const float* inputs    = (const float*)d_in[0];
    const float* title     = (const float*)d_in[1];
    const int*   nbr_batch = (const int*)d_in[2];
    const int*   nbr_job   = (const int*)d_in[3];
    const int*   nbr_title = (const int*)d_in[4];
    const int*   nbr_mask  = (const int*)d_in[5];
    float*       out       = (float*)d_out;

    const int rows = BB * PP;     // 32768
    dim3 grid(rows / 2);          // 2 rows (waves) per 128-thread block
    dim3 block(128);

    han_meta_kernel<<<grid, block, 0, stream>>>(
        inputs, title, nbr_batch, nbr_job, nbr_title, nbr_mask, out);
}